// Round 1
// baseline (1621.714 us; speedup 1.0000x reference)
//
#include <hip/hip_runtime.h>

typedef unsigned short u16;
typedef __attribute__((ext_vector_type(4))) float  f32x4;
typedef __attribute__((ext_vector_type(8))) short  short8;   // 8 bf16 = 4 VGPRs
typedef __attribute__((ext_vector_type(4))) unsigned short u16x4;

constexpr int T = 8192;   // tokens (4*2048)
constexpr int H = 1024;
constexpr int I = 4096;
constexpr int E = 8;

// ---------------- workspace layout (bytes) ----------------
constexpr size_t HDR_BYTES = 256;                       // cnt[8], cnt2[8], eoff[16], imp[8]
constexpr size_t RIDX_OFF  = HDR_BYTES;                 // int[2T]
constexpr size_t PROB_OFF  = RIDX_OFF  + (size_t)2*T*4; // float[2T]
constexpr size_t TKIDX_OFF = PROB_OFF  + (size_t)2*T*4; // int[2T]
constexpr size_t TOROW_OFF = TKIDX_OFF + (size_t)2*T*4; // int[2T]
constexpr size_t XBF_OFF   = TOROW_OFF + (size_t)2*T*4;            // bf16 [T][H]      16 MB
constexpr size_t W1_OFF    = XBF_OFF  + (size_t)T*H*2;             // bf16 [E][2I][H] 128 MB
constexpr size_t W2_OFF    = W1_OFF   + (size_t)E*2*I*H*2;         // bf16 [E][H][I]   64 MB
constexpr size_t HWS_OFF   = W2_OFF   + (size_t)E*H*I*2;           // bf16 [2T][I]    128 MB
constexpr size_t YWS_OFF   = HWS_OFF  + (size_t)2*T*I*2;           // bf16 [2T][H]     32 MB

__device__ __forceinline__ u16 f2bf(float f) {
  union { float f; unsigned int u; } v; v.f = f;
  unsigned int r = (v.u + 0x7FFFu + ((v.u >> 16) & 1u)) >> 16;
  return (u16)r;
}
__device__ __forceinline__ float bf2f(u16 u) {
  union { unsigned int u; float f; } v; v.u = ((unsigned int)u) << 16;
  return v.f;
}
// inline-asm MFMA: robust to builtin signature (short8 vs bf16x8) differences
__device__ __forceinline__ f32x4 mfma_16x16x32_bf16(short8 a, short8 b, f32x4 c) {
  asm("v_mfma_f32_16x16x32_bf16 %0, %1, %2, %0" : "+v"(c) : "v"(a), "v"(b));
  return c;
}

// ---------------- fp32 -> bf16 conversion ----------------
__global__ void f2bf_kernel(const float* __restrict__ src, u16* __restrict__ dst, int n4) {
  int i0 = blockIdx.x * blockDim.x + threadIdx.x;
  int stride = gridDim.x * blockDim.x;
  for (int i = i0; i < n4; i += stride) {
    f32x4 v = ((const f32x4*)src)[i];
    u16x4 o;
    o[0] = f2bf(v[0]); o[1] = f2bf(v[1]); o[2] = f2bf(v[2]); o[3] = f2bf(v[3]);
    ((u16x4*)dst)[i] = o;
  }
}

// ---------------- gating: logits, softmax, top-2, aux stats ----------------
// 1024 threads = 16 waves = 16 tokens per block; 512 blocks.
__global__ __launch_bounds__(1024) void gate_kernel(
    const float* __restrict__ x, const float* __restrict__ gw,
    int* __restrict__ cnt, float* __restrict__ imp,
    int* __restrict__ tkidx, float* __restrict__ probs) {
  __shared__ float simp[E];
  if (threadIdx.x < E) simp[threadIdx.x] = 0.f;
  __syncthreads();
  int wid  = threadIdx.x >> 6;
  int lane = threadIdx.x & 63;
  int tkn  = blockIdx.x * 16 + wid;

  float xi[16];
  const float* xr = x + (size_t)tkn * H;
  #pragma unroll
  for (int j = 0; j < 16; j++) xi[j] = xr[j * 64 + lane];

  float lg[E];
  #pragma unroll
  for (int e = 0; e < E; e++) {
    const float* w = gw + e * H;
    float s = 0.f;
    #pragma unroll
    for (int j = 0; j < 16; j++) s = fmaf(xi[j], w[j * 64 + lane], s);
    #pragma unroll
    for (int m = 1; m < 64; m <<= 1) s += __shfl_xor(s, m, 64);
    lg[e] = s;
  }
  // softmax (all lanes redundantly)
  float mx = lg[0];
  #pragma unroll
  for (int e = 1; e < E; e++) mx = fmaxf(mx, lg[e]);
  float p[E], s = 0.f;
  #pragma unroll
  for (int e = 0; e < E; e++) { p[e] = __expf(lg[e] - mx); s += p[e]; }
  float inv = 1.f / s;
  #pragma unroll
  for (int e = 0; e < E; e++) p[e] *= inv;
  // top-2 on logits (exact fp32 compare, first-index tie-break like lax.top_k)
  int i0 = 0;
  #pragma unroll
  for (int e = 1; e < E; e++) if (lg[e] > lg[i0]) i0 = e;
  int i1 = (i0 == 0) ? 1 : 0;
  #pragma unroll
  for (int e = 0; e < E; e++) if (e != i0 && lg[e] > lg[i1]) i1 = e;

  if (lane == 0) {
    float ps = p[i0] + p[i1] + 1e-9f;
    tkidx[2 * tkn]     = i0;  probs[2 * tkn]     = p[i0] / ps;
    tkidx[2 * tkn + 1] = i1;  probs[2 * tkn + 1] = p[i1] / ps;
    atomicAdd(&cnt[i0], 1);
    atomicAdd(&cnt[i1], 1);
    #pragma unroll
    for (int e = 0; e < E; e++) atomicAdd(&simp[e], p[e]);
  }
  __syncthreads();
  if (threadIdx.x < E) atomicAdd(&imp[threadIdx.x], simp[threadIdx.x]);
}

// ---------------- prefix offsets + aux loss ----------------
__global__ void scan_aux_kernel(const int* __restrict__ cnt, int* __restrict__ eoff,
                                const float* __restrict__ imp, float* __restrict__ outaux) {
  if (threadIdx.x == 0) {
    int s = 0;
    for (int e = 0; e < E; e++) { eoff[e] = s; s += cnt[e]; }
    eoff[E] = s;
    float a = 0.f;
    for (int e = 0; e < E; e++)
      a += ((float)cnt[e] / ((float)T * 2.f + 1e-9f)) * (imp[e] / (float)T);
    a = fminf(a * (float)E * 0.01f, 1.f);
    *outaux = a;
  }
}

// ---------------- token -> grouped-row assignment ----------------
__global__ void assign_kernel(const int* __restrict__ tkidx, const int* __restrict__ eoff,
                              int* __restrict__ cnt2, int* __restrict__ rowidx,
                              int* __restrict__ torow) {
  int tkn = blockIdx.x * blockDim.x + threadIdx.x;
  if (tkn >= T) return;
  #pragma unroll
  for (int k = 0; k < 2; k++) {
    int e = tkidx[2 * tkn + k];
    int pos = atomicAdd(&cnt2[e], 1);
    int row = eoff[e] + pos;
    rowidx[2 * tkn + k] = row;
    torow[row] = tkn;
  }
}

// ---------------- GEMM1: h = silu(x@Wg^T) * (x@Wu^T)  (gathered rows) ----------------
// tile 128x128, BK=64, 4 waves (2x2), wave tile 64x64 = 4x4 frags of 16x16.
// LDS XOR-swizzle (T2): 16B slot s of row r stored at slot s^(r&7) -> conflict-free reads.
__global__ __launch_bounds__(256, 2) void gemm1_kernel(
    const u16* __restrict__ xbf, const u16* __restrict__ w1, u16* __restrict__ hws,
    const int* __restrict__ cnt, const int* __restrict__ eoff, const int* __restrict__ torow) {
  const int e  = blockIdx.z;
  const int ce = cnt[e];
  const int m0 = blockIdx.x * 128;
  if (m0 >= ce) return;
  const int n0  = blockIdx.y * 128;
  const int off = eoff[e];
  const u16* w1e = w1 + (size_t)e * 2 * I * H;

  __shared__ __align__(16) u16 As[128 * 64];
  __shared__ __align__(16) u16 Bg[128 * 64];
  __shared__ __align__(16) u16 Bu[128 * 64];

  const int t    = threadIdx.x;
  const int lane = t & 63;
  const int wid  = t >> 6;
  const int wm   = (wid >> 1) * 64;
  const int wn   = (wid & 1) * 64;
  const int slot = t & 7;        // 16B k-chunk index
  const int srow = t >> 3;       // staging rows srow + i*32

  const u16* aptr[4];
  int brow[4], wdst[4];
  #pragma unroll
  for (int i = 0; i < 4; i++) {
    int r  = srow + i * 32;
    int gm = m0 + r;
    int tok = (gm < ce) ? torow[off + gm] : torow[off];
    aptr[i] = xbf + (size_t)tok * H + slot * 8;
    brow[i] = n0 + r;
    wdst[i] = r * 64 + ((slot ^ (r & 7)) * 8);
  }

  f32x4 accg[4][4], accu[4][4];
  f32x4 zero = {0.f, 0.f, 0.f, 0.f};
  #pragma unroll
  for (int a = 0; a < 4; a++)
    #pragma unroll
    for (int b = 0; b < 4; b++) { accg[a][b] = zero; accu[a][b] = zero; }

  for (int k0 = 0; k0 < H; k0 += 64) {
    short8 va[4], vg[4], vu[4];
    #pragma unroll
    for (int i = 0; i < 4; i++) {
      va[i] = *(const short8*)(aptr[i] + k0);
      vg[i] = *(const short8*)(w1e + (size_t)brow[i] * H + k0 + slot * 8);
      vu[i] = *(const short8*)(w1e + (size_t)(I + brow[i]) * H + k0 + slot * 8);
    }
    __syncthreads();
    #pragma unroll
    for (int i = 0; i < 4; i++) {
      *(short8*)&As[wdst[i]] = va[i];
      *(short8*)&Bg[wdst[i]] = vg[i];
      *(short8*)&Bu[wdst[i]] = vu[i];
    }
    __syncthreads();
    #pragma unroll
    for (int ks = 0; ks < 2; ks++) {
      short8 af[4], bg[4], bu[4];
      #pragma unroll
      for (int f = 0; f < 4; f++) {
        int ra = wm + f * 16 + (lane & 15);
        int sa = ((ks * 4) + (lane >> 4)) ^ (ra & 7);
        af[f] = *(const short8*)&As[ra * 64 + sa * 8];
        int rb = wn + f * 16 + (lane & 15);
        int sb = ((ks * 4) + (lane >> 4)) ^ (rb & 7);
        bg[f] = *(const short8*)&Bg[rb * 64 + sb * 8];
        bu[f] = *(const short8*)&Bu[rb * 64 + sb * 8];
      }
      #pragma unroll
      for (int fm = 0; fm < 4; fm++)
        #pragma unroll
        for (int fn = 0; fn < 4; fn++) {
          accg[fm][fn] = mfma_16x16x32_bf16(af[fm], bg[fn], accg[fm][fn]);
          accu[fm][fn] = mfma_16x16x32_bf16(af[fm], bu[fn], accu[fm][fn]);
        }
    }
  }
  // epilogue: h = silu(g)*u
  #pragma unroll
  for (int fm = 0; fm < 4; fm++)
    #pragma unroll
    for (int j = 0; j < 4; j++) {
      int row = wm + fm * 16 + (lane >> 4) * 4 + j;
      int gm  = m0 + row;
      if (gm < ce) {
        size_t rowbase = (size_t)(off + gm) * I + n0;
        #pragma unroll
        for (int fn = 0; fn < 4; fn++) {
          int col = wn + fn * 16 + (lane & 15);
          float g = accg[fm][fn][j];
          float u = accu[fm][fn][j];
          float hv = (g / (1.f + __expf(-g))) * u;
          hws[rowbase + col] = f2bf(hv);
        }
      }
    }
}

// ---------------- GEMM2: y = h @ down^T ----------------
__global__ __launch_bounds__(256, 2) void gemm2_kernel(
    const u16* __restrict__ hws, const u16* __restrict__ w2, u16* __restrict__ yws,
    const int* __restrict__ cnt, const int* __restrict__ eoff) {
  const int e  = blockIdx.z;
  const int ce = cnt[e];
  const int m0 = blockIdx.x * 128;
  if (m0 >= ce) return;
  const int n0  = blockIdx.y * 128;
  const int off = eoff[e];
  const u16* w2e = w2 + (size_t)e * H * I;

  __shared__ __align__(16) u16 As[128 * 64];
  __shared__ __align__(16) u16 Bs[128 * 64];

  const int t    = threadIdx.x;
  const int lane = t & 63;
  const int wid  = t >> 6;
  const int wm   = (wid >> 1) * 64;
  const int wn   = (wid & 1) * 64;
  const int slot = t & 7;
  const int srow = t >> 3;

  size_t arow[4]; int brow[4], wdst[4];
  #pragma unroll
  for (int i = 0; i < 4; i++) {
    int r  = srow + i * 32;
    int gm = m0 + r;
    int cr = (gm < ce) ? gm : (ce - 1);
    arow[i] = (size_t)(off + cr) * I;
    brow[i] = n0 + r;
    wdst[i] = r * 64 + ((slot ^ (r & 7)) * 8);
  }

  f32x4 acc[4][4];
  f32x4 zero = {0.f, 0.f, 0.f, 0.f};
  #pragma unroll
  for (int a = 0; a < 4; a++)
    #pragma unroll
    for (int b = 0; b < 4; b++) acc[a][b] = zero;

  for (int k0 = 0; k0 < I; k0 += 64) {
    short8 va[4], vb[4];
    #pragma unroll
    for (int i = 0; i < 4; i++) {
      va[i] = *(const short8*)(hws + arow[i] + k0 + slot * 8);
      vb[i] = *(const short8*)(w2e + (size_t)brow[i] * I + k0 + slot * 8);
    }
    __syncthreads();
    #pragma unroll
    for (int i = 0; i < 4; i++) {
      *(short8*)&As[wdst[i]] = va[i];
      *(short8*)&Bs[wdst[i]] = vb[i];
    }
    __syncthreads();
    #pragma unroll
    for (int ks = 0; ks < 2; ks++) {
      short8 af[4], bf[4];
      #pragma unroll
      for (int f = 0; f < 4; f++) {
        int ra = wm + f * 16 + (lane & 15);
        int sa = ((ks * 4) + (lane >> 4)) ^ (ra & 7);
        af[f] = *(const short8*)&As[ra * 64 + sa * 8];
        int rb = wn + f * 16 + (lane & 15);
        int sb = ((ks * 4) + (lane >> 4)) ^ (rb & 7);
        bf[f] = *(const short8*)&Bs[rb * 64 + sb * 8];
      }
      #pragma unroll
      for (int fm = 0; fm < 4; fm++)
        #pragma unroll
        for (int fn = 0; fn < 4; fn++)
          acc[fm][fn] = mfma_16x16x32_bf16(af[fm], bf[fn], acc[fm][fn]);
    }
  }
  #pragma unroll
  for (int fm = 0; fm < 4; fm++)
    #pragma unroll
    for (int j = 0; j < 4; j++) {
      int row = wm + fm * 16 + (lane >> 4) * 4 + j;
      int gm  = m0 + row;
      if (gm < ce) {
        size_t rowbase = (size_t)(off + gm) * H + n0;
        #pragma unroll
        for (int fn = 0; fn < 4; fn++) {
          int col = wn + fn * 16 + (lane & 15);
          yws[rowbase + col] = f2bf(acc[fm][fn][j]);
        }
      }
    }
}

// ---------------- combine: out[t] = p0*y[r0] + p1*y[r1] ----------------
__global__ void combine_kernel(const u16* __restrict__ yws, const int* __restrict__ rowidx,
                               const float* __restrict__ probs, float* __restrict__ out) {
  int tkn = blockIdx.x;
  int c   = threadIdx.x * 4;
  int r0 = rowidx[2 * tkn], r1 = rowidx[2 * tkn + 1];
  float p0 = probs[2 * tkn], p1 = probs[2 * tkn + 1];
  u16x4 a = *(const u16x4*)(yws + (size_t)r0 * H + c);
  u16x4 b = *(const u16x4*)(yws + (size_t)r1 * H + c);
  f32x4 o;
  #pragma unroll
  for (int j = 0; j < 4; j++) o[j] = p0 * bf2f(a[j]) + p1 * bf2f(b[j]);
  *(f32x4*)(out + (size_t)tkn * H + c) = o;
}

// ---------------- launch ----------------
extern "C" void kernel_launch(void* const* d_in, const int* in_sizes, int n_in,
                              void* d_out, int out_size, void* d_ws, size_t ws_size,
                              hipStream_t stream) {
  const float* x  = (const float*)d_in[0];
  const float* gw = (const float*)d_in[1];
  const float* w1 = (const float*)d_in[2];
  const float* w2 = (const float*)d_in[3];
  float* out = (float*)d_out;

  char* ws = (char*)d_ws;
  int*   cnt    = (int*)ws;
  int*   cnt2   = cnt + 8;
  int*   eoff   = cnt + 16;          // 16 ints reserved, 9 used
  float* imp    = (float*)(cnt + 32);
  int*   rowidx = (int*)(ws + RIDX_OFF);
  float* probs  = (float*)(ws + PROB_OFF);
  int*   tkidx  = (int*)(ws + TKIDX_OFF);
  int*   torow  = (int*)(ws + TOROW_OFF);
  u16*   xbf    = (u16*)(ws + XBF_OFF);
  u16*   w1bf   = (u16*)(ws + W1_OFF);
  u16*   w2bf   = (u16*)(ws + W2_OFF);
  u16*   hws    = (u16*)(ws + HWS_OFF);
  u16*   yws    = (u16*)(ws + YWS_OFF);

  hipMemsetAsync(d_ws, 0, HDR_BYTES, stream);

  f2bf_kernel<<<4096, 256, 0, stream>>>(x,  xbf,  (T * H) / 4);
  f2bf_kernel<<<4096, 256, 0, stream>>>(w1, w1bf, (E * 2 * I * H) / 4);
  f2bf_kernel<<<4096, 256, 0, stream>>>(w2, w2bf, (E * H * I) / 4);

  gate_kernel<<<T / 16, 1024, 0, stream>>>(x, gw, cnt, imp, tkidx, probs);
  scan_aux_kernel<<<1, 64, 0, stream>>>(cnt, eoff, imp, out + (size_t)T * H);
  assign_kernel<<<T / 256, 256, 0, stream>>>(tkidx, eoff, cnt2, rowidx, torow);

  gemm1_kernel<<<dim3(64, 32, 8), 256, 0, stream>>>(xbf, w1bf, hws, cnt, eoff, torow);
  gemm2_kernel<<<dim3(64, 8, 8), 256, 0, stream>>>(hws, w2bf, yws, cnt, eoff);

  combine_kernel<<<T, 256, 0, stream>>>(yws, rowidx, probs, out);
}

// Round 2
// 1597.433 us; speedup vs baseline: 1.0152x; 1.0152x over previous
//
#include <hip/hip_runtime.h>

typedef unsigned short u16;
typedef __attribute__((ext_vector_type(4))) float  f32x4;
typedef __attribute__((ext_vector_type(8))) short  short8;   // 8 bf16 = 4 VGPRs
typedef __attribute__((ext_vector_type(4))) unsigned short u16x4;

constexpr int T = 8192;   // tokens (4*2048)
constexpr int H = 1024;
constexpr int I = 4096;
constexpr int E = 8;

// ---------------- workspace layout (bytes) ----------------
constexpr size_t HDR_BYTES = 256;                       // cnt[8], cnt2[8], eoff[16], imp[8]
constexpr size_t RIDX_OFF  = HDR_BYTES;                 // int[2T]
constexpr size_t PROB_OFF  = RIDX_OFF  + (size_t)2*T*4; // float[2T]
constexpr size_t TKIDX_OFF = PROB_OFF  + (size_t)2*T*4; // int[2T]
constexpr size_t TOROW_OFF = TKIDX_OFF + (size_t)2*T*4; // int[2T]
constexpr size_t XBF_OFF   = TOROW_OFF + (size_t)2*T*4;            // bf16 [T][H]      16 MB
constexpr size_t W1_OFF    = XBF_OFF  + (size_t)T*H*2;             // bf16 [E][2I][H] 128 MB
constexpr size_t W2_OFF    = W1_OFF   + (size_t)E*2*I*H*2;         // bf16 [E][H][I]   64 MB
constexpr size_t HWS_OFF   = W2_OFF   + (size_t)E*H*I*2;           // bf16 [2T][I]    128 MB
constexpr size_t YWS_OFF   = HWS_OFF  + (size_t)2*T*I*2;           // bf16 [2T][H]     32 MB

__device__ __forceinline__ u16 f2bf(float f) {
  union { float f; unsigned int u; } v; v.f = f;
  unsigned int r = (v.u + 0x7FFFu + ((v.u >> 16) & 1u)) >> 16;
  return (u16)r;
}
__device__ __forceinline__ float bf2f(u16 u) {
  union { unsigned int u; float f; } v; v.u = ((unsigned int)u) << 16;
  return v.f;
}
__device__ __forceinline__ f32x4 mfma_16x16x32_bf16(short8 a, short8 b, f32x4 c) {
  asm("v_mfma_f32_16x16x32_bf16 %0, %1, %2, %0" : "+v"(c) : "v"(a), "v"(b));
  return c;
}

// async global -> LDS, 16B per lane. LDS dest is wave-uniform base + lane*16
// (we pass per-lane linear pointers; first lane's value is the wave base).
typedef __attribute__((address_space(1))) const unsigned int g_as1;
typedef __attribute__((address_space(3))) unsigned int l_as3;
__device__ __forceinline__ void gld16(const u16* g, u16* l) {
  __builtin_amdgcn_global_load_lds((g_as1*)g, (l_as3*)l, 16, 0, 0);
}

// ---------------- fp32 -> bf16 conversion ----------------
__global__ void f2bf_kernel(const float* __restrict__ src, u16* __restrict__ dst, int n4) {
  int i0 = blockIdx.x * blockDim.x + threadIdx.x;
  int stride = gridDim.x * blockDim.x;
  for (int i = i0; i < n4; i += stride) {
    f32x4 v = ((const f32x4*)src)[i];
    u16x4 o;
    o[0] = f2bf(v[0]); o[1] = f2bf(v[1]); o[2] = f2bf(v[2]); o[3] = f2bf(v[3]);
    ((u16x4*)dst)[i] = o;
  }
}

// ---------------- gating: logits, softmax, top-2, aux stats ----------------
__global__ __launch_bounds__(1024) void gate_kernel(
    const float* __restrict__ x, const float* __restrict__ gw,
    int* __restrict__ cnt, float* __restrict__ imp,
    int* __restrict__ tkidx, float* __restrict__ probs) {
  __shared__ float simp[E];
  if (threadIdx.x < E) simp[threadIdx.x] = 0.f;
  __syncthreads();
  int wid  = threadIdx.x >> 6;
  int lane = threadIdx.x & 63;
  int tkn  = blockIdx.x * 16 + wid;

  float xi[16];
  const float* xr = x + (size_t)tkn * H;
  #pragma unroll
  for (int j = 0; j < 16; j++) xi[j] = xr[j * 64 + lane];

  float lg[E];
  #pragma unroll
  for (int e = 0; e < E; e++) {
    const float* w = gw + e * H;
    float s = 0.f;
    #pragma unroll
    for (int j = 0; j < 16; j++) s = fmaf(xi[j], w[j * 64 + lane], s);
    #pragma unroll
    for (int m = 1; m < 64; m <<= 1) s += __shfl_xor(s, m, 64);
    lg[e] = s;
  }
  float mx = lg[0];
  #pragma unroll
  for (int e = 1; e < E; e++) mx = fmaxf(mx, lg[e]);
  float p[E], s = 0.f;
  #pragma unroll
  for (int e = 0; e < E; e++) { p[e] = __expf(lg[e] - mx); s += p[e]; }
  float inv = 1.f / s;
  #pragma unroll
  for (int e = 0; e < E; e++) p[e] *= inv;
  int i0 = 0;
  #pragma unroll
  for (int e = 1; e < E; e++) if (lg[e] > lg[i0]) i0 = e;
  int i1 = (i0 == 0) ? 1 : 0;
  #pragma unroll
  for (int e = 0; e < E; e++) if (e != i0 && lg[e] > lg[i1]) i1 = e;

  if (lane == 0) {
    float ps = p[i0] + p[i1] + 1e-9f;
    tkidx[2 * tkn]     = i0;  probs[2 * tkn]     = p[i0] / ps;
    tkidx[2 * tkn + 1] = i1;  probs[2 * tkn + 1] = p[i1] / ps;
    atomicAdd(&cnt[i0], 1);
    atomicAdd(&cnt[i1], 1);
    #pragma unroll
    for (int e = 0; e < E; e++) atomicAdd(&simp[e], p[e]);
  }
  __syncthreads();
  if (threadIdx.x < E) atomicAdd(&imp[threadIdx.x], simp[threadIdx.x]);
}

// ---------------- prefix offsets + aux loss ----------------
__global__ void scan_aux_kernel(const int* __restrict__ cnt, int* __restrict__ eoff,
                                const float* __restrict__ imp, float* __restrict__ outaux) {
  if (threadIdx.x == 0) {
    int s = 0;
    for (int e = 0; e < E; e++) { eoff[e] = s; s += cnt[e]; }
    eoff[E] = s;
    float a = 0.f;
    for (int e = 0; e < E; e++)
      a += ((float)cnt[e] / ((float)T * 2.f + 1e-9f)) * (imp[e] / (float)T);
    a = fminf(a * (float)E * 0.01f, 1.f);
    *outaux = a;
  }
}

// ---------------- token -> grouped-row assignment ----------------
__global__ void assign_kernel(const int* __restrict__ tkidx, const int* __restrict__ eoff,
                              int* __restrict__ cnt2, int* __restrict__ rowidx,
                              int* __restrict__ torow) {
  int tkn = blockIdx.x * blockDim.x + threadIdx.x;
  if (tkn >= T) return;
  #pragma unroll
  for (int k = 0; k < 2; k++) {
    int e = tkidx[2 * tkn + k];
    int pos = atomicAdd(&cnt2[e], 1);
    int row = eoff[e] + pos;
    rowidx[2 * tkn + k] = row;
    torow[row] = tkn;
  }
}

// ---------------- GEMM1: h = silu(x@Wg^T) * (x@Wu^T)  (gathered rows) ----------------
// tile 128x128, BK=64, 4 waves (2x2). global_load_lds staging: LDS is written
// LINEARLY (lane*16B); the XOR swizzle (slot s' holds global slot s'^(r&7)) is
// applied on the GLOBAL source address; reads use the same involution.
__global__ __launch_bounds__(256, 2) void gemm1_kernel(
    const u16* __restrict__ xbf, const u16* __restrict__ w1, u16* __restrict__ hws,
    const int* __restrict__ cnt, const int* __restrict__ eoff, const int* __restrict__ torow) {
  const int e  = blockIdx.z;
  const int ce = cnt[e];
  const int m0 = blockIdx.x * 128;
  if (m0 >= ce) return;
  const int n0  = blockIdx.y * 128;
  const int off = eoff[e];
  const u16* w1e = w1 + (size_t)e * 2 * I * H;

  __shared__ __align__(16) u16 As[128 * 64];
  __shared__ __align__(16) u16 Bg[128 * 64];
  __shared__ __align__(16) u16 Bu[128 * 64];

  const int t    = threadIdx.x;
  const int lane = t & 63;
  const int wid  = t >> 6;
  const int wm   = (wid >> 1) * 64;
  const int wn   = (wid & 1) * 64;
  const int srow = t >> 3;       // staging row (t>>3) + i*32
  const int sp   = t & 7;        // linear 16B slot within row

  const u16* agp[4]; const u16* bgp[4]; const u16* bup[4];
  #pragma unroll
  for (int i = 0; i < 4; i++) {
    int r  = srow + i * 32;
    int sg = sp ^ (r & 7);               // pre-swizzled global slot
    int gm = m0 + r;
    int tok = (gm < ce) ? torow[off + gm] : torow[off];
    agp[i] = xbf + (size_t)tok * H + sg * 8;
    int rb = n0 + r;
    bgp[i] = w1e + (size_t)rb * H + sg * 8;
    bup[i] = w1e + (size_t)(I + rb) * H + sg * 8;
  }

  f32x4 accg[4][4], accu[4][4];
  f32x4 zero = {0.f, 0.f, 0.f, 0.f};
  #pragma unroll
  for (int a = 0; a < 4; a++)
    #pragma unroll
    for (int b = 0; b < 4; b++) { accg[a][b] = zero; accu[a][b] = zero; }

  for (int k0 = 0; k0 < H; k0 += 64) {
    __syncthreads();                     // prev-iter LDS reads done
    #pragma unroll
    for (int i = 0; i < 4; i++) {
      gld16(agp[i] + k0, &As[i * 2048 + t * 8]);
      gld16(bgp[i] + k0, &Bg[i * 2048 + t * 8]);
      gld16(bup[i] + k0, &Bu[i * 2048 + t * 8]);
    }
    __syncthreads();                     // compiler drains vmcnt before barrier
    #pragma unroll
    for (int ks = 0; ks < 2; ks++) {
      short8 af[4], bg[4], bu[4];
      #pragma unroll
      for (int f = 0; f < 4; f++) {
        int ra = wm + f * 16 + (lane & 15);
        int sa = ((ks * 4) + (lane >> 4)) ^ (ra & 7);
        af[f] = *(const short8*)&As[ra * 64 + sa * 8];
        int rb = wn + f * 16 + (lane & 15);
        int sb = ((ks * 4) + (lane >> 4)) ^ (rb & 7);
        bg[f] = *(const short8*)&Bg[rb * 64 + sb * 8];
        bu[f] = *(const short8*)&Bu[rb * 64 + sb * 8];
      }
      #pragma unroll
      for (int fm = 0; fm < 4; fm++)
        #pragma unroll
        for (int fn = 0; fn < 4; fn++) {
          accg[fm][fn] = mfma_16x16x32_bf16(af[fm], bg[fn], accg[fm][fn]);
          accu[fm][fn] = mfma_16x16x32_bf16(af[fm], bu[fn], accu[fm][fn]);
        }
    }
  }
  // epilogue: h = silu(g)*u
  #pragma unroll
  for (int fm = 0; fm < 4; fm++)
    #pragma unroll
    for (int j = 0; j < 4; j++) {
      int row = wm + fm * 16 + (lane >> 4) * 4 + j;
      int gm  = m0 + row;
      if (gm < ce) {
        size_t rowbase = (size_t)(off + gm) * I + n0;
        #pragma unroll
        for (int fn = 0; fn < 4; fn++) {
          int col = wn + fn * 16 + (lane & 15);
          float g = accg[fm][fn][j];
          float u = accu[fm][fn][j];
          float hv = (g / (1.f + __expf(-g))) * u;
          hws[rowbase + col] = f2bf(hv);
        }
      }
    }
}

// ---------------- GEMM2: y = h @ down^T ----------------
__global__ __launch_bounds__(256, 2) void gemm2_kernel(
    const u16* __restrict__ hws, const u16* __restrict__ w2, u16* __restrict__ yws,
    const int* __restrict__ cnt, const int* __restrict__ eoff) {
  const int e  = blockIdx.z;
  const int ce = cnt[e];
  const int m0 = blockIdx.x * 128;
  if (m0 >= ce) return;
  const int n0  = blockIdx.y * 128;
  const int off = eoff[e];
  const u16* w2e = w2 + (size_t)e * H * I;

  __shared__ __align__(16) u16 As[128 * 64];
  __shared__ __align__(16) u16 Bs[128 * 64];

  const int t    = threadIdx.x;
  const int lane = t & 63;
  const int wid  = t >> 6;
  const int wm   = (wid >> 1) * 64;
  const int wn   = (wid & 1) * 64;
  const int srow = t >> 3;
  const int sp   = t & 7;

  const u16* agp[4]; const u16* bgp[4];
  #pragma unroll
  for (int i = 0; i < 4; i++) {
    int r  = srow + i * 32;
    int sg = sp ^ (r & 7);
    int gm = m0 + r;
    int cr = (gm < ce) ? gm : (ce - 1);
    agp[i] = hws + (size_t)(off + cr) * I + sg * 8;
    int rb = n0 + r;
    bgp[i] = w2e + (size_t)rb * I + sg * 8;
  }

  f32x4 acc[4][4];
  f32x4 zero = {0.f, 0.f, 0.f, 0.f};
  #pragma unroll
  for (int a = 0; a < 4; a++)
    #pragma unroll
    for (int b = 0; b < 4; b++) acc[a][b] = zero;

  for (int k0 = 0; k0 < I; k0 += 64) {
    __syncthreads();
    #pragma unroll
    for (int i = 0; i < 4; i++) {
      gld16(agp[i] + k0, &As[i * 2048 + t * 8]);
      gld16(bgp[i] + k0, &Bs[i * 2048 + t * 8]);
    }
    __syncthreads();
    #pragma unroll
    for (int ks = 0; ks < 2; ks++) {
      short8 af[4], bf[4];
      #pragma unroll
      for (int f = 0; f < 4; f++) {
        int ra = wm + f * 16 + (lane & 15);
        int sa = ((ks * 4) + (lane >> 4)) ^ (ra & 7);
        af[f] = *(const short8*)&As[ra * 64 + sa * 8];
        int rb = wn + f * 16 + (lane & 15);
        int sb = ((ks * 4) + (lane >> 4)) ^ (rb & 7);
        bf[f] = *(const short8*)&Bs[rb * 64 + sb * 8];
      }
      #pragma unroll
      for (int fm = 0; fm < 4; fm++)
        #pragma unroll
        for (int fn = 0; fn < 4; fn++)
          acc[fm][fn] = mfma_16x16x32_bf16(af[fm], bf[fn], acc[fm][fn]);
    }
  }
  #pragma unroll
  for (int fm = 0; fm < 4; fm++)
    #pragma unroll
    for (int j = 0; j < 4; j++) {
      int row = wm + fm * 16 + (lane >> 4) * 4 + j;
      int gm  = m0 + row;
      if (gm < ce) {
        size_t rowbase = (size_t)(off + gm) * H + n0;
        #pragma unroll
        for (int fn = 0; fn < 4; fn++) {
          int col = wn + fn * 16 + (lane & 15);
          yws[rowbase + col] = f2bf(acc[fm][fn][j]);
        }
      }
    }
}

// ---------------- combine: out[t] = p0*y[r0] + p1*y[r1] ----------------
__global__ void combine_kernel(const u16* __restrict__ yws, const int* __restrict__ rowidx,
                               const float* __restrict__ probs, float* __restrict__ out) {
  int tkn = blockIdx.x;
  int c   = threadIdx.x * 4;
  int r0 = rowidx[2 * tkn], r1 = rowidx[2 * tkn + 1];
  float p0 = probs[2 * tkn], p1 = probs[2 * tkn + 1];
  u16x4 a = *(const u16x4*)(yws + (size_t)r0 * H + c);
  u16x4 b = *(const u16x4*)(yws + (size_t)r1 * H + c);
  f32x4 o;
  #pragma unroll
  for (int j = 0; j < 4; j++) o[j] = p0 * bf2f(a[j]) + p1 * bf2f(b[j]);
  *(f32x4*)(out + (size_t)tkn * H + c) = o;
}

// ---------------- launch ----------------
extern "C" void kernel_launch(void* const* d_in, const int* in_sizes, int n_in,
                              void* d_out, int out_size, void* d_ws, size_t ws_size,
                              hipStream_t stream) {
  const float* x  = (const float*)d_in[0];
  const float* gw = (const float*)d_in[1];
  const float* w1 = (const float*)d_in[2];
  const float* w2 = (const float*)d_in[3];
  float* out = (float*)d_out;

  char* ws = (char*)d_ws;
  int*   cnt    = (int*)ws;
  int*   cnt2   = cnt + 8;
  int*   eoff   = cnt + 16;
  float* imp    = (float*)(cnt + 32);
  int*   rowidx = (int*)(ws + RIDX_OFF);
  float* probs  = (float*)(ws + PROB_OFF);
  int*   tkidx  = (int*)(ws + TKIDX_OFF);
  int*   torow  = (int*)(ws + TOROW_OFF);
  u16*   xbf    = (u16*)(ws + XBF_OFF);
  u16*   w1bf   = (u16*)(ws + W1_OFF);
  u16*   w2bf   = (u16*)(ws + W2_OFF);
  u16*   hws    = (u16*)(ws + HWS_OFF);
  u16*   yws    = (u16*)(ws + YWS_OFF);

  hipMemsetAsync(d_ws, 0, HDR_BYTES, stream);

  f2bf_kernel<<<4096, 256, 0, stream>>>(x,  xbf,  (T * H) / 4);
  f2bf_kernel<<<4096, 256, 0, stream>>>(w1, w1bf, (E * 2 * I * H) / 4);
  f2bf_kernel<<<4096, 256, 0, stream>>>(w2, w2bf, (E * H * I) / 4);

  gate_kernel<<<T / 16, 1024, 0, stream>>>(x, gw, cnt, imp, tkidx, probs);
  scan_aux_kernel<<<1, 64, 0, stream>>>(cnt, eoff, imp, out + (size_t)T * H);
  assign_kernel<<<T / 256, 256, 0, stream>>>(tkidx, eoff, cnt2, rowidx, torow);

  gemm1_kernel<<<dim3(32, 32, 8), 256, 0, stream>>>(xbf, w1bf, hws, cnt, eoff, torow);
  gemm2_kernel<<<dim3(32, 8, 8), 256, 0, stream>>>(hws, w2bf, yws, cnt, eoff);

  combine_kernel<<<T, 256, 0, stream>>>(yws, rowidx, probs, out);
}